// Round 1
// baseline (274.087 us; speedup 1.0000x reference)
//
#include <hip/hip_runtime.h>
#include <math.h>

// Problem shape (fixed by reference setup_inputs):
//   features:  (B=8, N=65536, C=64) fp32
//   coarse_map:(B=8, NP=16384, NS=32) int32 in [0, N)
//   out:       (B, NP, C) fp32 = max over NS gathered rows
constexpr int B  = 8;
constexpr int N  = 65536;
constexpr int C  = 64;      // floats per feature row (256 B)
constexpr int NP = 16384;
constexpr int NS = 32;
constexpr int C4 = C / 4;   // 16 float4 per row

// 16 lanes cooperate on one output point; lane j owns channels [4j, 4j+4).
// Each gathered row read = 16 lanes x float4 = one contiguous 256 B segment.
__global__ __launch_bounds__(256) void gather_max_kernel(
    const float4* __restrict__ feat,   // B*N*C4 float4
    const int*    __restrict__ cmap,   // B*NP*NS int32
    float4*       __restrict__ out)    // B*NP*C4 float4
{
    const int tid   = blockIdx.x * blockDim.x + threadIdx.x;
    const int point = tid >> 4;            // global point id in [0, B*NP)
    const int j     = tid & 15;            // lane-within-group = float4 index
    if (point >= B * NP) return;

    const int    b        = point >> 14;   // point / NP (NP = 16384 = 2^14)
    const size_t featBase = (size_t)b * N * C4;

    // Cooperative index load: lane j holds idx[2j], idx[2j+1] (coalesced 128 B/group).
    const int2 myIdx = ((const int2*)(cmap + (size_t)point * NS))[j];

    const int lane  = threadIdx.x & 63;
    const int gbase = lane & ~15;          // base lane of this 16-lane group

    float4 m = make_float4(-INFINITY, -INFINITY, -INFINITY, -INFINITY);
#pragma unroll
    for (int s = 0; s < NS; ++s) {
        // Owner lane for sample s is gbase + (s>>1); it holds the value in .x/.y.
        const int v   = (s & 1) ? myIdx.y : myIdx.x;
        const int idx = __shfl(v, gbase + (s >> 1), 64);
        const float4 f = feat[featBase + (size_t)idx * C4 + j];
        m.x = fmaxf(m.x, f.x);
        m.y = fmaxf(m.y, f.y);
        m.z = fmaxf(m.z, f.z);
        m.w = fmaxf(m.w, f.w);
    }

    // Coalesced float4 store: consecutive lanes -> consecutive float4s.
    out[(size_t)point * C4 + j] = m;
}

extern "C" void kernel_launch(void* const* d_in, const int* in_sizes, int n_in,
                              void* d_out, int out_size, void* d_ws, size_t ws_size,
                              hipStream_t stream) {
    const float4* feat = (const float4*)d_in[0];
    const int*    cmap = (const int*)d_in[1];
    float4*       out  = (float4*)d_out;

    const int totalThreads = B * NP * 16;         // 16 lanes per point
    const int block = 256;
    const int grid  = (totalThreads + block - 1) / block;  // 8192
    gather_max_kernel<<<grid, block, 0, stream>>>(feat, cmap, out);
}